// Round 5
// baseline (361.055 us; speedup 1.0000x reference)
//
#include <hip/hip_runtime.h>

// Monarch block-diag: out[b, s*64+l] = sum_r w2[l,s,r] * sum_p x[b, r*64+p] * w1[r,l,p]
// B=8192, N=4096, blocks 64. fp32 in/out; bf16 MFMA compute.
//
// R5 structure (2 blocks/CU + direct stores): r4 confirmed the write-amp mechanism is
// TEMPORAL splitting of 256-B out granules (WRITE hit 1.07x ideal) but left BW util at
// 26% -- 128 KiB LDS forced 1 block/CU, fully serializing load/compute/store phases.
// Changes:
//   - b-tile 8 (grid 1024), 512 thr (8 waves), Y = [8b][64 l][64 r] bf16 = 64 KiB LDS
//     -> 2 independent blocks/CU overlap their phases (A stores while B loads).
//     MFMA M=16 rows carry duplicated b-rows (m&7); quads 2-3 results discarded
//     (MFMA is ~2% utilized -- the waste is free).
//   - NO O-stage: stage-2 drains accumulators straight to global in 2 s-half passes.
//     Temporal granule completeness is preserved (each (b,s) granule gets all 64 l
//     within one pass window), which r4 proved is the only thing that matters.
//     Deletes 512 KiB/block LDS traffic and 4 of 5 barriers (ONE __syncthreads left).

typedef __bf16 bf16x8 __attribute__((ext_vector_type(8)));
typedef float  float4v __attribute__((ext_vector_type(4)));

__global__ __launch_bounds__(256)
void cvt_weights(const float* __restrict__ w1, const float* __restrict__ w2,
                 __bf16* __restrict__ wb) {
    const int i = (blockIdx.x * 256 + threadIdx.x) * 8;  // grid 128 -> i < 262144
    float4v a = *(const float4v*)(w1 + i);
    float4v b = *(const float4v*)(w1 + i + 4);
    bf16x8 v;
    v[0]=(__bf16)a[0]; v[1]=(__bf16)a[1]; v[2]=(__bf16)a[2]; v[3]=(__bf16)a[3];
    v[4]=(__bf16)b[0]; v[5]=(__bf16)b[1]; v[6]=(__bf16)b[2]; v[7]=(__bf16)b[3];
    *(bf16x8*)(wb + i) = v;
    a = *(const float4v*)(w2 + i);
    b = *(const float4v*)(w2 + i + 4);
    v[0]=(__bf16)a[0]; v[1]=(__bf16)a[1]; v[2]=(__bf16)a[2]; v[3]=(__bf16)a[3];
    v[4]=(__bf16)b[0]; v[5]=(__bf16)b[1]; v[6]=(__bf16)b[2]; v[7]=(__bf16)b[3];
    *(bf16x8*)(wb + 262144 + i) = v;
}

__global__ __launch_bounds__(512, 4)
void monarch_fused(const float* __restrict__ x,
                   const __bf16* __restrict__ w1b,
                   const __bf16* __restrict__ w2b,
                   float* __restrict__ out)
{
    // Y: [bl(8)][q(64)][kchunk(8) xor-swz][elem(8)] bf16 = 64 KiB dynamic LDS.
    // Swizzle cs = kchunk ^ (q&7) ^ (bl&7): bank set depends only on cs -> balanced
    // (8 dwords/bank wave-b128 minimum on writes; reads dedup via m/m+8 broadcast).
    extern __shared__ __align__(16) unsigned char smem[];
    __bf16* Y = (__bf16*)smem;

    const int tid  = threadIdx.x;
    const int wid  = tid >> 6;      // 0..7
    const int lane = tid & 63;
    const int m    = lane & 15;     // MFMA: A-M / B-N / D-col index
    const int quad = lane >> 4;     // MFMA: A/B K-group, D row-group
    const int b0   = blockIdx.x * 8;
    const int brow = m & 7;         // real b-row (rows 8..15 of A are duplicates)

    // ---- stage-1: wave = k-chunk kw; preload x A-frags (k = kw*8+j, p = h*32+quad*8+e)
    const int kw = wid;
    bf16x8 xa[8][2];
    {
        const float* xp = x + (long)(b0 + brow) * 4096 + kw * 512 + quad * 8;
        #pragma unroll
        for (int j = 0; j < 8; ++j) {
            #pragma unroll
            for (int h = 0; h < 2; ++h) {
                float4v lo = *(const float4v*)(xp + j * 64 + h * 32);
                float4v hi = *(const float4v*)(xp + j * 64 + h * 32 + 4);
                bf16x8 v;
                v[0]=(__bf16)lo[0]; v[1]=(__bf16)lo[1]; v[2]=(__bf16)lo[2]; v[3]=(__bf16)lo[3];
                v[4]=(__bf16)hi[0]; v[5]=(__bf16)hi[1]; v[6]=(__bf16)hi[2]; v[7]=(__bf16)hi[3];
                xa[j][h] = v;
            }
        }
    }

    // ---- stage-1 compute: Y[b][q][k] for k in [kw*8,+8), all 64 q (4 tiles) ----
    #pragma unroll
    for (int qt = 0; qt < 4; ++qt) {
        float4v acc[8];
        #pragma unroll
        for (int j = 0; j < 8; ++j) {
            const int k = kw * 8 + j;
            const __bf16* w1p = w1b + ((k * 64 + qt * 16 + m) * 64) + quad * 8;
            bf16x8 bb0 = *(const bf16x8*)(w1p);
            bf16x8 bb1 = *(const bf16x8*)(w1p + 32);
            float4v c = {0.f, 0.f, 0.f, 0.f};
            c = __builtin_amdgcn_mfma_f32_16x16x32_bf16(xa[j][0], bb0, c, 0, 0, 0);
            c = __builtin_amdgcn_mfma_f32_16x16x32_bf16(xa[j][1], bb1, c, 0, 0, 0);
            acc[j] = c;
        }
        // D: lane holds D[b = quad*4+reg][q = qt*16+m]; rows >=8 are duplicates -> skip.
        if (quad < 2) {
            #pragma unroll
            for (int reg = 0; reg < 4; ++reg) {
                const int bl = quad * 4 + reg;        // 0..7
                const int q  = qt * 16 + m;
                const int cs = kw ^ (m & 7) ^ (bl & 7);
                bf16x8 v;
                #pragma unroll
                for (int j = 0; j < 8; ++j) v[j] = (__bf16)acc[j][reg];
                *(bf16x8*)(&Y[((bl * 64 + q) * 8 + cs) * 8]) = v;
            }
        }
    }
    __syncthreads();  // the kernel's ONLY barrier

    // ---- stage-2: wave = (st = wid>>2, lgrp = wid&3); 2 passes over s-halves.
    // Per pass: s = (h2*2+st)*16+m, l = lgrp*16+li; acc2[16] drains straight to global.
    const int st   = wid >> 2;
    const int lgrp = wid & 3;

    #pragma unroll
    for (int h2 = 0; h2 < 2; ++h2) {
        const int s = (h2 * 2 + st) * 16 + m;
        float4v acc2[16];
        #pragma unroll
        for (int li = 0; li < 16; ++li) acc2[li] = (float4v){0.f, 0.f, 0.f, 0.f};

        #pragma unroll
        for (int h = 0; h < 2; ++h) {
            #pragma unroll
            for (int li = 0; li < 16; ++li) {
                const int l   = lgrp * 16 + li;
                const int cs2 = (h * 4 + quad) ^ (l & 7) ^ (m & 7);
                // A2[b = brow][r = h*32 + quad*8 + e] = Y[brow][l][r] (m/m+8 broadcast)
                bf16x8 a2 = *(const bf16x8*)(&Y[((brow * 64 + l) * 8 + cs2) * 8]);
                bf16x8 b2 = *(const bf16x8*)(w2b + l * 4096 + s * 64 + h * 32 + quad * 8);
                acc2[li] = __builtin_amdgcn_mfma_f32_16x16x32_bf16(a2, b2, acc2[li], 0, 0, 0);
            }
        }

        // Direct store: lane holds out[b0+quad*4+reg][s][l range]; rows >=8 dup -> skip.
        // All 64 l of each (b,s) 256-B granule land within this pass's window
        // (4 lgrp waves x 4 li4) -> temporally complete, no RMW (r4-confirmed mechanism).
        if (quad < 2) {
            #pragma unroll
            for (int li4 = 0; li4 < 4; ++li4) {
                #pragma unroll
                for (int reg = 0; reg < 4; ++reg) {
                    const int bl = quad * 4 + reg;    // 0..7
                    float4v v = { acc2[li4 * 4 + 0][reg], acc2[li4 * 4 + 1][reg],
                                  acc2[li4 * 4 + 2][reg], acc2[li4 * 4 + 3][reg] };
                    *(float4v*)(out + (long)(b0 + bl) * 4096 + s * 64 + lgrp * 16 + li4 * 4) = v;
                }
            }
        }
    }
}

extern "C" void kernel_launch(void* const* d_in, const int* in_sizes, int n_in,
                              void* d_out, int out_size, void* d_ws, size_t ws_size,
                              hipStream_t stream) {
    const float* x  = (const float*)d_in[0];
    const float* w1 = (const float*)d_in[1];
    const float* w2 = (const float*)d_in[2];
    float* out = (float*)d_out;
    __bf16* wb = (__bf16*)d_ws;   // w1b at [0, 262144), w2b at [262144, 524288)

    hipLaunchKernelGGL(cvt_weights, dim3(128), dim3(256), 0, stream, w1, w2, wb);
    hipLaunchKernelGGL(monarch_fused, dim3(8192 / 8), dim3(512), 65536, stream,
                       x, wb, wb + 262144, out);
}